// Round 6
// baseline (3146.023 us; speedup 1.0000x reference)
//
#include <hip/hip_runtime.h>
#include <hip/hip_bf16.h>
#include <math.h>

#define DEV __device__ __forceinline__

typedef __attribute__((ext_vector_type(8))) short bf16x8;
typedef __attribute__((ext_vector_type(4))) float f32x4;
typedef __attribute__((ext_vector_type(4))) int i32x4;

DEV float sigmoidf_(float x) { return 1.0f / (1.0f + __expf(-x)); }

DEV unsigned bf16rne(float x) {
  unsigned b = __float_as_uint(x);
  return (b + 0x7FFFu + ((b >> 16) & 1u)) >> 16;
}
// pack fp32 -> (hi bf16 <<16) | (lo bf16)   [hi = rne(x), lo = rne(x - hi)]
DEV unsigned packhl(float v) {
  const unsigned hi = bf16rne(v);
  const float hf = __uint_as_float(hi << 16);
  const unsigned lo = bf16rne(v - hf);
  return (hi << 16) | lo;
}

DEV f32x4 mm(bf16x8 a, bf16x8 b, f32x4 c) {
  return __builtin_amdgcn_mfma_f32_16x16x32_bf16(a, b, c, 0, 0, 0);
}

#define R10(OP) OP(0) OP(1) OP(2) OP(3) OP(4) OP(5) OP(6) OP(7) OP(8) OP(9)
#define R11(OP) R10(OP) OP(10)

#define DOT_O(base) (sA[(base)+0]*hO0 + sA[(base)+1]*hO1 + sA[(base)+2]*hO2 + sA[(base)+3]*hO3 \
                   + sA[(base)+4]*hO4 + sA[(base)+5]*hO5 + sA[(base)+6]*hO6 + sA[(base)+7]*hO7 \
                   + sA[(base)+8]*hO8 + sA[(base)+9]*hO9)
#define DOT_D(base) (sA[(base)+0]*hD0 + sA[(base)+1]*hD1 + sA[(base)+2]*hD2 + sA[(base)+3]*hD3 \
                   + sA[(base)+4]*hD4 + sA[(base)+5]*hD5 + sA[(base)+6]*hD6 + sA[(base)+7]*hD7 \
                   + sA[(base)+8]*hD8 + sA[(base)+9]*hD9 + sA[(base)+10]*hD10)

// ---------------- temporal GRU (tiny, unchanged) ----------------
DEV float gstep(float x, float h, const float* k, const float* rk, const float* bb) {
  const float z  = sigmoidf_(fmaf(x, k[0], bb[0]) + fmaf(h, rk[0], bb[3]));
  const float r  = sigmoidf_(fmaf(x, k[1], bb[1]) + fmaf(h, rk[1], bb[4]));
  const float hh = tanhf(fmaf(x, k[2], bb[2]) + r * fmaf(h, rk[2], bb[5]));
  return z * h + (1.f - z) * hh;
}

__global__ void __launch_bounds__(64, 1)
temporal_kernel(const float* __restrict__ T, const float* __restrict__ GK,
                const float* __restrict__ GRK, const float* __restrict__ GB,
                const float* __restrict__ WO, const int* __restrict__ IDX,
                float* __restrict__ tp) {
  const int i = threadIdx.x;
  __shared__ float fb[3][75];
  __shared__ float gg[3][75];
  if (i < 3) {
    float k0[3], k1[3], rk0[3], rk1[3];
#pragma unroll
    for (int q = 0; q < 3; ++q) {
      k0[q]  = GK[i * 6 + q];      k1[q]  = GK[i * 6 + 3 + q];
      rk0[q] = GRK[i * 6 + q];     rk1[q] = GRK[i * 6 + 3 + q];
    }
    const float* B0 = GB + i * 12;
    const float* B1 = GB + i * 12 + 6;
    float h = 0.f;
    for (int s = 0; s < 75; ++s) { h = gstep(T[i * 75 + s], h, k0, rk0, B0); fb[i][s] = h; }
    h = 0.f;
    for (int s = 0; s < 75; ++s) { h = gstep(fb[i][74 - s], h, k1, rk1, B1); gg[i][s] = h; }
    const float wo = WO[i];
    float mx = -1e30f;
    for (int s = 0; s < 75; ++s) mx = fmaxf(mx, gg[i][s] * wo);
    float sum = 0.f;
    for (int s = 0; s < 75; ++s) { const float e = __expf(gg[i][s] * wo - mx); fb[i][s] = e; sum += e; }
    const float inv = 1.f / sum;
    for (int j = 0; j < 60; ++j) tp[i * 60 + j] = fb[i][IDX[j]] * inv;
  }
}

// ---------------- weight prep: pack 9 gate mats into MFMA B-frags ----------------
// frag order per mat: fi = base + (kb*4 + n)*2 + hl ; each frag = 1KB: lane*16B = 8 bf16
// lane l holds B[k = kb*32 + 8*(l>>4) + e][col = n*16 + (l&15)], e=0..7
// mats: WzR(0) WrR(32) WmR(64) WzO(96) WrO(144) WmO(192) WzD(240) WrD(272) WmD(304); total 336 frags
__global__ void __launch_bounds__(64, 1) prep_kernel(
    const float* __restrict__ WzR, const float* __restrict__ WrR, const float* __restrict__ WmR,
    const float* __restrict__ WzO, const float* __restrict__ WrO, const float* __restrict__ WmO,
    const float* __restrict__ WzD, const float* __restrict__ WrD, const float* __restrict__ WmD,
    char* __restrict__ ws) {
  const int fi = blockIdx.x;
  const int l = threadIdx.x;
  const float* W; int base;
  if      (fi <  32) { W = WzR; base = 0;   }
  else if (fi <  64) { W = WrR; base = 32;  }
  else if (fi <  96) { W = WmR; base = 64;  }
  else if (fi < 144) { W = WzO; base = 96;  }
  else if (fi < 192) { W = WrO; base = 144; }
  else if (fi < 240) { W = WmO; base = 192; }
  else if (fi < 272) { W = WzD; base = 240; }
  else if (fi < 304) { W = WrD; base = 272; }
  else               { W = WmD; base = 304; }
  const int local = fi - base;
  const int hl = local & 1;
  const int kn = local >> 1;
  const int n  = kn & 3;
  const int kb = kn >> 2;
  union { unsigned short s[8]; i32x4 i; } U;
#pragma unroll
  for (int e = 0; e < 8; ++e) {
    const int k = kb * 32 + 8 * (l >> 4) + e;
    const int col = n * 16 + (l & 15);
    const float v = W[k * 64 + col];
    const unsigned hi = bf16rne(v);
    if (hl == 0) U.s[e] = (unsigned short)hi;
    else {
      const float hf = __uint_as_float(hi << 16);
      U.s[e] = (unsigned short)bf16rne(v - hf);
    }
  }
  *(i32x4*)(ws + 1024 + (size_t)fi * 1024 + l * 16) = U.i;
}

// ---------------- MFMA helpers ----------------
DEV bf16x8 bfrag(const char* ws, int fi) {
  union { i32x4 i; bf16x8 v; } U;
  U.i = *(const i32x4*)(ws + 1024 + (size_t)fi * 1024 + threadIdx.x * 16);
  return U.v;
}

// op LDS element = packed (hi<<16|lo). Build hi/lo A-frags from 8 consecutive k.
DEV void afrag(const unsigned* opx, int idx, bf16x8& ah, bf16x8& al) {
  const i32x4 q0 = *(const i32x4*)(opx + idx);
  const i32x4 q1 = *(const i32x4*)(opx + idx + 4);
  union { unsigned u[4]; bf16x8 v; } H, L;
  H.u[0] = (((unsigned)q0[0]) >> 16) | (((unsigned)q0[1]) & 0xFFFF0000u);
  H.u[1] = (((unsigned)q0[2]) >> 16) | (((unsigned)q0[3]) & 0xFFFF0000u);
  H.u[2] = (((unsigned)q1[0]) >> 16) | (((unsigned)q1[1]) & 0xFFFF0000u);
  H.u[3] = (((unsigned)q1[2]) >> 16) | (((unsigned)q1[3]) & 0xFFFF0000u);
  L.u[0] = (((unsigned)q0[0]) & 0xFFFFu) | (((unsigned)q0[1]) << 16);
  L.u[1] = (((unsigned)q0[2]) & 0xFFFFu) | (((unsigned)q0[3]) << 16);
  L.u[2] = (((unsigned)q1[0]) & 0xFFFFu) | (((unsigned)q1[1]) << 16);
  L.u[3] = (((unsigned)q1[2]) & 0xFFFFu) | (((unsigned)q1[3]) << 16);
  ah = H.v; al = L.v;
}

template<int KS>
DEV void gate_zr(const unsigned* opx, int opb, int S, int rowsm1,
                 const char* ws, int fiZ, int fiR,
                 f32x4& z0, f32x4& z1, f32x4& z2, f32x4& z3,
                 f32x4& r0, f32x4& r1, f32x4& r2, f32x4& r3) {
  const int l = threadIdx.x;
  int ar = l & 15; if (ar > rowsm1) ar = rowsm1;
  const int rbase = opb + ar * S + 8 * (l >> 4);
#pragma unroll
  for (int kb = 0; kb < KS; ++kb) {
    bf16x8 ah, al; afrag(opx, rbase + kb * 32, ah, al);
#define NN(n, ZA, RA) { \
    bf16x8 bzh = bfrag(ws, fiZ + (kb*4+n)*2), bzl = bfrag(ws, fiZ + (kb*4+n)*2+1); \
    bf16x8 brh = bfrag(ws, fiR + (kb*4+n)*2), brl = bfrag(ws, fiR + (kb*4+n)*2+1); \
    ZA = mm(ah, bzh, ZA); ZA = mm(ah, bzl, ZA); ZA = mm(al, bzh, ZA); \
    RA = mm(ah, brh, RA); RA = mm(ah, brl, RA); RA = mm(al, brh, RA); }
    NN(0, z0, r0) NN(1, z1, r1) NN(2, z2, r2) NN(3, z3, r3)
#undef NN
  }
}

template<int KS>
DEV void gate_m(const unsigned* opx, int opb, int S, int rowsm1,
                const char* ws, int fiM,
                f32x4& m0, f32x4& m1, f32x4& m2, f32x4& m3) {
  const int l = threadIdx.x;
  int ar = l & 15; if (ar > rowsm1) ar = rowsm1;
  const int rbase = opb + ar * S + 8 * (l >> 4);
#pragma unroll
  for (int kb = 0; kb < KS; ++kb) {
    bf16x8 ah, al; afrag(opx, rbase + kb * 32, ah, al);
#define NN(n, MA) { \
    bf16x8 bh = bfrag(ws, fiM + (kb*4+n)*2), bl = bfrag(ws, fiM + (kb*4+n)*2+1); \
    MA = mm(ah, bh, MA); MA = mm(ah, bl, MA); MA = mm(al, bh, MA); }
    NN(0, m0) NN(1, m1) NN(2, m2) NN(3, m3)
#undef NN
  }
}

// stash one 16x64 result tile to ep[row][col] (verified D layout: col=l&15, row=4*(l>>4)+q)
DEV void stash(float* ep, f32x4 a0, f32x4 a1, f32x4 a2, f32x4 a3) {
  const int l = threadIdx.x;
  const int rw = 4 * (l >> 4);
  const int cc = l & 15;
#pragma unroll
  for (int q = 0; q < 4; ++q) {
    ep[(rw + q) * 65 + cc]      = a0[q];
    ep[(rw + q) * 65 + 16 + cc] = a1[q];
    ep[(rw + q) * 65 + 32 + cc] = a2[q];
    ep[(rw + q) * 65 + 48 + cc] = a3[q];
  }
}

// op staging layout (u32 packed hi|lo), strides chosen 16B-aligned + 2-way-bank-free
#define S_O 196
#define S_D 132
#define S_R 132
#define OPO 0
#define OPD (10 * S_O)              // 1960
#define OPR (OPD + 11 * S_D)        // 3412
#define OPN (OPR + 2 * S_R)         // 3676 u32 total
// frag index bases
#define FI_ZR 0
#define FI_RR 32
#define FI_MR 64
#define FI_ZO 96
#define FI_RO 144
#define FI_MO 192
#define FI_ZD 240
#define FI_RD 272
#define FI_MD 304

// ---------------- main: 1 wave per batch element, MFMA gate matvecs ----------------
__global__ void __launch_bounds__(64, 2) ggnn_mfma(
    const float* __restrict__ X, const float* __restrict__ A,
    const float* __restrict__ WgR, const float* __restrict__ bgR,
    const float* __restrict__ WgO, const float* __restrict__ bgO,
    const float* __restrict__ WgD, const float* __restrict__ bgD,
    const float* __restrict__ bmR, const float* __restrict__ bmO, const float* __restrict__ bmD,
    const float* __restrict__ W1R, const float* __restrict__ b1R, const float* __restrict__ W2R,
    const float* __restrict__ W1O, const float* __restrict__ b1O, const float* __restrict__ W2O,
    const float* __restrict__ W1D, const float* __restrict__ b1D, const float* __restrict__ W2D,
    const char* __restrict__ ws, const float* __restrict__ tp, float* __restrict__ out) {
  const int b = blockIdx.x;
  const int c = threadIdx.x;  // 0..63

  __shared__ __align__(16) float smem[1408];   // X stage / ep tile / score stash
  __shared__ float sA[484];
  __shared__ __align__(16) unsigned opx[OPN];  // packed operand staging
  float* ep = smem;

  const float* Xb = X + (size_t)b * 880;
  const float* Ab = A + (size_t)b * 484;
  for (int t = c; t < 880; t += 64) smem[t] = Xb[t];
  for (int t = c; t < 484; t += 64) sA[t] = Ab[t];
  __syncthreads();

  // ---------------- phase 0 (VALU, proven) ----------------
  float hR;
#define DECLHO(i) float hO##i;
  R10(DECLHO)
#undef DECLHO
#define DECLHD(i) float hD##i;
  R11(DECLHD)
#undef DECLHD
  {
    float aR = bgR[c], cO = bgO[c], cD = bgD[c];
#pragma unroll 4
    for (int k = 0; k < 40; ++k) {
      const float x = smem[k];
      aR = fmaf(x, WgR[k * 64 + c], aR);
      cO = fmaf(x, WgO[k * 64 + c], cO);
      cD = fmaf(x, WgD[k * 64 + c], cD);
    }
    hR = tanhf(aR);
#define DECLAO(i) float aO##i = cO;
    R10(DECLAO)
#undef DECLAO
#define DECLAD(i) float aD##i = cD;
    R11(DECLAD)
#undef DECLAD
#pragma unroll 2
    for (int k = 0; k < 30; ++k) {
      const float wo_ = WgO[(40 + k) * 64 + c];
      const float wd_ = WgD[(40 + k) * 64 + c];
#define AOSTEP(i) aO##i = fmaf(smem[(1 + i) * 40 + 10 + k], wo_, aO##i);
      R10(AOSTEP)
#undef AOSTEP
#define ADSTEP(i) aD##i = fmaf(smem[(11 + i) * 40 + 10 + k], wd_, aD##i);
      R11(ADSTEP)
#undef ADSTEP
    }
#define TANHO(i) hO##i = tanhf(aO##i);
    R10(TANHO)
#undef TANHO
#define TANHD(i) hD##i = tanhf(aD##i);
    R11(TANHD)
#undef TANHD
  }
  __syncthreads();

  const float bmRc = bmR[c], bmOc = bmO[c], bmDc = bmD[c];

  // ---------------- 3 GRU iterations ----------------
  for (int it = 0; it < 3; ++it) {
    // stage operands (old h): [h | n] packed hi|lo
    opx[OPR + c]      = packhl(hR);
    opx[OPR + 64 + c] = packhl(DOT_O(1));
#define SG(i) opx[OPO + i * S_O + c] = packhl(hO##i); \
              opx[OPO + i * S_O + 64 + c] = packhl(sA[(1 + i) * 22] * hR); \
              opx[OPO + i * S_O + 128 + c] = packhl(DOT_D((1 + i) * 22 + 11));
    R10(SG)
#undef SG
#define SG(i) opx[OPD + i * S_D + c] = packhl(hD##i); \
              opx[OPD + i * S_D + 64 + c] = packhl(DOT_O((11 + i) * 22 + 1));
    R11(SG)
#undef SG
    __syncthreads();  // order u32 writes vs i32x4 A-frag reads

    // ===== gate O (10 rows, K=192) =====
    {
      f32x4 z0{0,0,0,0}, z1{0,0,0,0}, z2{0,0,0,0}, z3{0,0,0,0};
      f32x4 r0{0,0,0,0}, r1{0,0,0,0}, r2{0,0,0,0}, r3{0,0,0,0};
      gate_zr<6>(opx, OPO, S_O, 9, ws, FI_ZO, FI_RO, z0, z1, z2, z3, r0, r1, r2, r3);
      stash(ep, z0, z1, z2, z3);
#define RD(i) const float zO##i = sigmoidf_(ep[(i) * 65 + c]);
      R10(RD)
#undef RD
      stash(ep, r0, r1, r2, r3);
#define RD(i) { const float rr = sigmoidf_(ep[(i) * 65 + c]); opx[OPO + i * S_O + c] = packhl(hO##i * rr); }
      R10(RD)
#undef RD
      __syncthreads();
      f32x4 m0{0,0,0,0}, m1{0,0,0,0}, m2{0,0,0,0}, m3{0,0,0,0};
      gate_m<6>(opx, OPO, S_O, 9, ws, FI_MO, m0, m1, m2, m3);
      stash(ep, m0, m1, m2, m3);
#define RD(i) hO##i = (1.f - zO##i) * hO##i + zO##i * tanhf(ep[(i) * 65 + c] + bmOc);
      R10(RD)
#undef RD
    }

    // ===== gate D (11 rows, K=128) =====
    {
      f32x4 z0{0,0,0,0}, z1{0,0,0,0}, z2{0,0,0,0}, z3{0,0,0,0};
      f32x4 r0{0,0,0,0}, r1{0,0,0,0}, r2{0,0,0,0}, r3{0,0,0,0};
      gate_zr<4>(opx, OPD, S_D, 10, ws, FI_ZD, FI_RD, z0, z1, z2, z3, r0, r1, r2, r3);
      stash(ep, z0, z1, z2, z3);
#define RD(i) const float zD##i = sigmoidf_(ep[(i) * 65 + c]);
      R11(RD)
#undef RD
      stash(ep, r0, r1, r2, r3);
#define RD(i) { const float rr = sigmoidf_(ep[(i) * 65 + c]); opx[OPD + i * S_D + c] = packhl(hD##i * rr); }
      R11(RD)
#undef RD
      __syncthreads();
      f32x4 m0{0,0,0,0}, m1{0,0,0,0}, m2{0,0,0,0}, m3{0,0,0,0};
      gate_m<4>(opx, OPD, S_D, 10, ws, FI_MD, m0, m1, m2, m3);
      stash(ep, m0, m1, m2, m3);
#define RD(i) hD##i = (1.f - zD##i) * hD##i + zD##i * tanhf(ep[(i) * 65 + c] + bmDc);
      R11(RD)
#undef RD
    }

    // ===== gate R (1 row, K=128) =====
    {
      f32x4 z0{0,0,0,0}, z1{0,0,0,0}, z2{0,0,0,0}, z3{0,0,0,0};
      f32x4 r0{0,0,0,0}, r1{0,0,0,0}, r2{0,0,0,0}, r3{0,0,0,0};
      gate_zr<4>(opx, OPR, S_R, 0, ws, FI_ZR, FI_RR, z0, z1, z2, z3, r0, r1, r2, r3);
      stash(ep, z0, z1, z2, z3);
      const float zR_ = sigmoidf_(ep[c]);
      stash(ep, r0, r1, r2, r3);
      { const float rr = sigmoidf_(ep[c]); opx[OPR + c] = packhl(hR * rr); }
      __syncthreads();
      f32x4 m0{0,0,0,0}, m1{0,0,0,0}, m2{0,0,0,0}, m3{0,0,0,0};
      gate_m<4>(opx, OPR, S_R, 0, ws, FI_MR, m0, m1, m2, m3);
      stash(ep, m0, m1, m2, m3);
      hR = (1.f - zR_) * hR + zR_ * tanhf(ep[c] + bmRc);
    }
    __syncthreads();
  }

  // ---------------- scores (VALU, proven) ----------------
  smem[c] = hR;
#define STASH_O(i) smem[(1 + i) * 64 + c] = hO##i;
  R10(STASH_O)
#undef STASH_O
#define STASH_D(i) smem[(11 + i) * 64 + c] = hD##i;
  R11(STASH_D)
#undef STASH_D
  __syncthreads();

  const int g = c >> 4;
  const int c1 = c & 15;
  float pR = 0.f, pO = 0.f, pD = 0.f;
  for (int rr = g; rr < 22; rr += 4) {
    const float* W1; const float* b1; const float* W2;
    if (rr == 0)      { W1 = W1R; b1 = b1R; W2 = W2R; }
    else if (rr < 11) { W1 = W1O; b1 = b1O; W2 = W2O; }
    else              { W1 = W1D; b1 = b1D; W2 = W2D; }
    float a = b1[c1];
#pragma unroll 8
    for (int kk = 0; kk < 64; ++kk) {
      const int k = (kk + (g << 4)) & 63;
      a = fmaf(smem[rr * 64 + k], W1[k * 16 + c1], a);
    }
    const float t = tanhf(a) * W2[c1];
    if (rr == 0) pR += t;
    else if (rr < 11) pO += t;
    else pD += t;
  }
#pragma unroll
  for (int off = 32; off >= 1; off >>= 1) {
    pR += __shfl_xor(pR, off, 64);
    pO += __shfl_xor(pO, off, 64);
    pD += __shfl_xor(pD, off, 64);
  }
  if (c < 60) {
    out[(size_t)b * 60 + c] = pR * tp[c] + pO * tp[60 + c] + pD * tp[120 + c];
  }
}

// ---------------- fallback: round-4 kernel (no ws needed beyond tp) ----------------
__global__ void __launch_bounds__(64, 2) ggnn_fallback(
    const float* __restrict__ X, const float* __restrict__ A,
    const float* __restrict__ WgR, const float* __restrict__ bgR,
    const float* __restrict__ WgO, const float* __restrict__ bgO,
    const float* __restrict__ WgD, const float* __restrict__ bgD,
    const float* __restrict__ WzR, const float* __restrict__ WrR,
    const float* __restrict__ WmR, const float* __restrict__ bmR,
    const float* __restrict__ WzO, const float* __restrict__ WrO,
    const float* __restrict__ WmO, const float* __restrict__ bmO,
    const float* __restrict__ WzD, const float* __restrict__ WrD,
    const float* __restrict__ WmD, const float* __restrict__ bmD,
    const float* __restrict__ W1R, const float* __restrict__ b1R, const float* __restrict__ W2R,
    const float* __restrict__ W1O, const float* __restrict__ b1O, const float* __restrict__ W2O,
    const float* __restrict__ W1D, const float* __restrict__ b1D, const float* __restrict__ W2D,
    const float* __restrict__ tp, float* __restrict__ out) {
  const int b = blockIdx.x;
  const int c = threadIdx.x;
  __shared__ __align__(16) float smem[3456];
  __shared__ float sA[484];
  const float* Xb = X + (size_t)b * 880;
  const float* Ab = A + (size_t)b * 484;
  for (int t = c; t < 880; t += 64) smem[t] = Xb[t];
  for (int t = c; t < 484; t += 64) sA[t] = Ab[t];
  __syncthreads();
  float hR;
#define DECLHO(i) float hO##i;
  R10(DECLHO)
#undef DECLHO
#define DECLHD(i) float hD##i;
  R11(DECLHD)
#undef DECLHD
  {
    float aR = bgR[c], cO = bgO[c], cD = bgD[c];
#pragma unroll 4
    for (int k = 0; k < 40; ++k) {
      const float x = smem[k];
      aR = fmaf(x, WgR[k * 64 + c], aR);
      cO = fmaf(x, WgO[k * 64 + c], cO);
      cD = fmaf(x, WgD[k * 64 + c], cD);
    }
    hR = tanhf(aR);
#define DECLAO(i) float aO##i = cO;
    R10(DECLAO)
#undef DECLAO
#define DECLAD(i) float aD##i = cD;
    R11(DECLAD)
#undef DECLAD
#pragma unroll 2
    for (int k = 0; k < 30; ++k) {
      const float wo_ = WgO[(40 + k) * 64 + c];
      const float wd_ = WgD[(40 + k) * 64 + c];
#define AOSTEP(i) aO##i = fmaf(smem[(1 + i) * 40 + 10 + k], wo_, aO##i);
      R10(AOSTEP)
#undef AOSTEP
#define ADSTEP(i) aD##i = fmaf(smem[(11 + i) * 40 + 10 + k], wd_, aD##i);
      R11(ADSTEP)
#undef ADSTEP
    }
#define TANHO(i) hO##i = tanhf(aO##i);
    R10(TANHO)
#undef TANHO
#define TANHD(i) hD##i = tanhf(aD##i);
    R11(TANHD)
#undef TANHD
  }
  for (int it = 0; it < 3; ++it) {
    __syncthreads();
    smem[c] = hR;
    smem[64 + c] = DOT_O(1);
#define STAGEO(i) smem[128 + i * 192 + c] = hO##i; \
                  smem[128 + i * 192 + 64 + c] = sA[(1 + i) * 22] * hR; \
                  smem[128 + i * 192 + 128 + c] = DOT_D((1 + i) * 22 + 11);
    R10(STAGEO)
#undef STAGEO
#define STAGEDD(i) smem[2048 + i * 128 + c] = hD##i; \
                   smem[2048 + i * 128 + 64 + c] = DOT_O((11 + i) * 22 + 1);
    R11(STAGEDD)
#undef STAGEDD
    __syncthreads();
    {
      float az = 0.f, ar = 0.f;
#pragma unroll 2
      for (int k4 = 0; k4 < 128; k4 += 4) {
        const float wa0 = WzR[(k4 + 0) * 64 + c], wa1 = WzR[(k4 + 1) * 64 + c];
        const float wa2 = WzR[(k4 + 2) * 64 + c], wa3 = WzR[(k4 + 3) * 64 + c];
        const float wb0 = WrR[(k4 + 0) * 64 + c], wb1 = WrR[(k4 + 1) * 64 + c];
        const float wb2 = WrR[(k4 + 2) * 64 + c], wb3 = WrR[(k4 + 3) * 64 + c];
        const float4 v = *reinterpret_cast<const float4*>(&smem[k4]);
        az = fmaf(v.x, wa0, az); az = fmaf(v.y, wa1, az);
        az = fmaf(v.z, wa2, az); az = fmaf(v.w, wa3, az);
        ar = fmaf(v.x, wb0, ar); ar = fmaf(v.y, wb1, ar);
        ar = fmaf(v.z, wb2, ar); ar = fmaf(v.w, wb3, ar);
      }
      const float z = sigmoidf_(az);
      const float r = sigmoidf_(ar);
      __syncthreads();
      smem[c] = hR * r;
      __syncthreads();
      float am = bmR[c];
#pragma unroll 2
      for (int k4 = 0; k4 < 128; k4 += 4) {
        const float w0 = WmR[(k4 + 0) * 64 + c], w1 = WmR[(k4 + 1) * 64 + c];
        const float w2 = WmR[(k4 + 2) * 64 + c], w3 = WmR[(k4 + 3) * 64 + c];
        const float4 v = *reinterpret_cast<const float4*>(&smem[k4]);
        am = fmaf(v.x, w0, am); am = fmaf(v.y, w1, am);
        am = fmaf(v.z, w2, am); am = fmaf(v.w, w3, am);
      }
      hR = (1.f - z) * hR + z * tanhf(am);
    }
    {
#define DECLZR(i) float az##i = 0.f, ar##i = 0.f;
      R10(DECLZR)
#undef DECLZR
#pragma unroll 2
      for (int k4 = 0; k4 < 192; k4 += 4) {
        const float wa0 = WzO[(k4 + 0) * 64 + c], wa1 = WzO[(k4 + 1) * 64 + c];
        const float wa2 = WzO[(k4 + 2) * 64 + c], wa3 = WzO[(k4 + 3) * 64 + c];
        const float wb0 = WrO[(k4 + 0) * 64 + c], wb1 = WrO[(k4 + 1) * 64 + c];
        const float wb2 = WrO[(k4 + 2) * 64 + c], wb3 = WrO[(k4 + 3) * 64 + c];
#define MSTEP(i) { const float4 v = *reinterpret_cast<const float4*>(&smem[128 + i * 192 + k4]); \
        az##i = fmaf(v.x, wa0, az##i); az##i = fmaf(v.y, wa1, az##i); \
        az##i = fmaf(v.z, wa2, az##i); az##i = fmaf(v.w, wa3, az##i); \
        ar##i = fmaf(v.x, wb0, ar##i); ar##i = fmaf(v.y, wb1, ar##i); \
        ar##i = fmaf(v.z, wb2, ar##i); ar##i = fmaf(v.w, wb3, ar##i); }
        R10(MSTEP)
#undef MSTEP
      }
#define SIGZR(i) const float z##i = sigmoidf_(az##i); const float r##i = sigmoidf_(ar##i);
      R10(SIGZR)
#undef SIGZR
      __syncthreads();
#define STAGEHR(i) smem[128 + i * 192 + c] = hO##i * r##i;
      R10(STAGEHR)
#undef STAGEHR
      __syncthreads();
#define DECLAM(i) float am##i = bmO[c];
      R10(DECLAM)
#undef DECLAM
#pragma unroll 2
      for (int k4 = 0; k4 < 192; k4 += 4) {
        const float w0 = WmO[(k4 + 0) * 64 + c], w1 = WmO[(k4 + 1) * 64 + c];
        const float w2 = WmO[(k4 + 2) * 64 + c], w3 = WmO[(k4 + 3) * 64 + c];
#define MSTEP(i) { const float4 v = *reinterpret_cast<const float4*>(&smem[128 + i * 192 + k4]); \
        am##i = fmaf(v.x, w0, am##i); am##i = fmaf(v.y, w1, am##i); \
        am##i = fmaf(v.z, w2, am##i); am##i = fmaf(v.w, w3, am##i); }
        R10(MSTEP)
#undef MSTEP
      }
#define UPDO(i) hO##i = (1.f - z##i) * hO##i + z##i * tanhf(am##i);
      R10(UPDO)
#undef UPDO
    }
    {
#define DECLZR(i) float az##i = 0.f, ar##i = 0.f;
      R11(DECLZR)
#undef DECLZR
#pragma unroll 2
      for (int k4 = 0; k4 < 128; k4 += 4) {
        const float wa0 = WzD[(k4 + 0) * 64 + c], wa1 = WzD[(k4 + 1) * 64 + c];
        const float wa2 = WzD[(k4 + 2) * 64 + c], wa3 = WzD[(k4 + 3) * 64 + c];
        const float wb0 = WrD[(k4 + 0) * 64 + c], wb1 = WrD[(k4 + 1) * 64 + c];
        const float wb2 = WrD[(k4 + 2) * 64 + c], wb3 = WrD[(k4 + 3) * 64 + c];
#define MSTEP(i) { const float4 v = *reinterpret_cast<const float4*>(&smem[2048 + i * 128 + k4]); \
        az##i = fmaf(v.x, wa0, az##i); az##i = fmaf(v.y, wa1, az##i); \
        az##i = fmaf(v.z, wa2, az##i); az##i = fmaf(v.w, wa3, az##i); \
        ar##i = fmaf(v.x, wb0, ar##i); ar##i = fmaf(v.y, wb1, ar##i); \
        ar##i = fmaf(v.z, wb2, ar##i); ar##i = fmaf(v.w, wb3, ar##i); }
        R11(MSTEP)
#undef MSTEP
      }
#define SIGZR(i) const float z##i = sigmoidf_(az##i); const float r##i = sigmoidf_(ar##i);
      R11(SIGZR)
#undef SIGZR
      __syncthreads();
#define STAGEHR(i) smem[2048 + i * 128 + c] = hD##i * r##i;
      R11(STAGEHR)
#undef STAGEHR
      __syncthreads();
#define DECLAM(i) float am##i = bmD[c];
      R11(DECLAM)
#undef DECLAM
#pragma unroll 2
      for (int k4 = 0; k4 < 128; k4 += 4) {
        const float w0 = WmD[(k4 + 0) * 64 + c], w1 = WmD[(k4 + 1) * 64 + c];
        const float w2 = WmD[(k4 + 2) * 64 + c], w3 = WmD[(k4 + 3) * 64 + c];
#define MSTEP(i) { const float4 v = *reinterpret_cast<const float4*>(&smem[2048 + i * 128 + k4]); \
        am##i = fmaf(v.x, w0, am##i); am##i = fmaf(v.y, w1, am##i); \
        am##i = fmaf(v.z, w2, am##i); am##i = fmaf(v.w, w3, am##i); }
        R11(MSTEP)
#undef MSTEP
      }
#define UPDD(i) hD##i = (1.f - z##i) * hD##i + z##i * tanhf(am##i);
      R11(UPDD)
#undef UPDD
    }
  }
  __syncthreads();
  smem[c] = hR;
#define STASH_O(i) smem[(1 + i) * 64 + c] = hO##i;
  R10(STASH_O)
#undef STASH_O
#define STASH_D(i) smem[(11 + i) * 64 + c] = hD##i;
  R11(STASH_D)
#undef STASH_D
  __syncthreads();
  const int g = c >> 4;
  const int c1 = c & 15;
  float pR = 0.f, pO = 0.f, pD = 0.f;
  for (int rr = g; rr < 22; rr += 4) {
    const float* W1; const float* b1; const float* W2;
    if (rr == 0)      { W1 = W1R; b1 = b1R; W2 = W2R; }
    else if (rr < 11) { W1 = W1O; b1 = b1O; W2 = W2O; }
    else              { W1 = W1D; b1 = b1D; W2 = W2D; }
    float a = b1[c1];
#pragma unroll 8
    for (int kk = 0; kk < 64; ++kk) {
      const int k = (kk + (g << 4)) & 63;
      a = fmaf(smem[rr * 64 + k], W1[k * 16 + c1], a);
    }
    const float t = tanhf(a) * W2[c1];
    if (rr == 0) pR += t;
    else if (rr < 11) pO += t;
    else pD += t;
  }
#pragma unroll
  for (int off = 32; off >= 1; off >>= 1) {
    pR += __shfl_xor(pR, off, 64);
    pO += __shfl_xor(pO, off, 64);
    pD += __shfl_xor(pD, off, 64);
  }
  if (c < 60) {
    out[(size_t)b * 60 + c] = pR * tp[c] + pO * tp[60 + c] + pD * tp[120 + c];
  }
}

extern "C" void kernel_launch(void* const* d_in, const int* in_sizes, int n_in,
                              void* d_out, int out_size, void* d_ws, size_t ws_size,
                              hipStream_t stream) {
  const float* X   = (const float*)d_in[0];
  const float* A   = (const float*)d_in[1];
  const float* WgR = (const float*)d_in[2];
  const float* bgR = (const float*)d_in[3];
  const float* WgO = (const float*)d_in[4];
  const float* bgO = (const float*)d_in[5];
  const float* WgD = (const float*)d_in[6];
  const float* bgD = (const float*)d_in[7];
  const float* WzR = (const float*)d_in[8];
  const float* WrR = (const float*)d_in[9];
  const float* WmR = (const float*)d_in[10];
  const float* bmR = (const float*)d_in[11];
  const float* WzO = (const float*)d_in[12];
  const float* WrO = (const float*)d_in[13];
  const float* WmO = (const float*)d_in[14];
  const float* bmO = (const float*)d_in[15];
  const float* WzD = (const float*)d_in[16];
  const float* WrD = (const float*)d_in[17];
  const float* WmD = (const float*)d_in[18];
  const float* bmD = (const float*)d_in[19];
  const float* W1R = (const float*)d_in[20];
  const float* b1R = (const float*)d_in[21];
  const float* W2R = (const float*)d_in[22];
  const float* W1O = (const float*)d_in[23];
  const float* b1O = (const float*)d_in[24];
  const float* W2O = (const float*)d_in[25];
  const float* W1D = (const float*)d_in[26];
  const float* b1D = (const float*)d_in[27];
  const float* W2D = (const float*)d_in[28];
  const float* Tmp = (const float*)d_in[29];
  const float* GK  = (const float*)d_in[30];
  const float* GRK = (const float*)d_in[31];
  const float* GB  = (const float*)d_in[32];
  const float* WO  = (const float*)d_in[33];
  const int*   IDX = (const int*)d_in[34];

  float* tp = (float*)d_ws;
  char*  ws = (char*)d_ws;
  const int B = in_sizes[0] / 880;
  const size_t WS_NEEDED = 1024 + 336 * 1024;

  hipLaunchKernelGGL(temporal_kernel, dim3(1), dim3(64), 0, stream, Tmp, GK, GRK, GB, WO, IDX, tp);

  if (ws_size >= WS_NEEDED) {
    hipLaunchKernelGGL(prep_kernel, dim3(336), dim3(64), 0, stream,
                       WzR, WrR, WmR, WzO, WrO, WmO, WzD, WrD, WmD, ws);
    hipLaunchKernelGGL(ggnn_mfma, dim3(B), dim3(64), 0, stream,
                       X, A, WgR, bgR, WgO, bgO, WgD, bgD,
                       bmR, bmO, bmD,
                       W1R, b1R, W2R, W1O, b1O, W2O, W1D, b1D, W2D,
                       (const char*)ws, (const float*)tp, (float*)d_out);
  } else {
    hipLaunchKernelGGL(ggnn_fallback, dim3(B), dim3(64), 0, stream,
                       X, A, WgR, bgR, WgO, bgO, WgD, bgD,
                       WzR, WrR, WmR, bmR, WzO, WrO, WmO, bmO, WzD, WrD, WmD, bmD,
                       W1R, b1R, W2R, W1O, b1O, W2O, W1D, b1D, W2D,
                       tp, (float*)d_out);
  }
}

// Round 7
// 1133.068 us; speedup vs baseline: 2.7766x; 2.7766x over previous
//
#include <hip/hip_runtime.h>
#include <hip/hip_bf16.h>
#include <math.h>

#define DEV __device__ __forceinline__

DEV float sigmoidf_(float x) { return 1.0f / (1.0f + __expf(-x)); }

#define R10(OP) OP(0) OP(1) OP(2) OP(3) OP(4) OP(5) OP(6) OP(7) OP(8) OP(9)
#define R11(OP) R10(OP) OP(10)

// dot of sA[base..base+9] with hO scalars (sA entries are wave-uniform)
#define DOT_O(base) (sA[(base)+0]*hO0 + sA[(base)+1]*hO1 + sA[(base)+2]*hO2 + sA[(base)+3]*hO3 \
                   + sA[(base)+4]*hO4 + sA[(base)+5]*hO5 + sA[(base)+6]*hO6 + sA[(base)+7]*hO7 \
                   + sA[(base)+8]*hO8 + sA[(base)+9]*hO9)
#define DOT_D(base) (sA[(base)+0]*hD0 + sA[(base)+1]*hD1 + sA[(base)+2]*hD2 + sA[(base)+3]*hD3 \
                   + sA[(base)+4]*hD4 + sA[(base)+5]*hD5 + sA[(base)+6]*hD6 + sA[(base)+7]*hD7 \
                   + sA[(base)+8]*hD8 + sA[(base)+9]*hD9 + sA[(base)+10]*hD10)

DEV float gstep(float x, float h, const float* k, const float* rk, const float* bb) {
  const float z  = sigmoidf_(fmaf(x, k[0], bb[0]) + fmaf(h, rk[0], bb[3]));
  const float r  = sigmoidf_(fmaf(x, k[1], bb[1]) + fmaf(h, rk[1], bb[4]));
  const float hh = tanhf(fmaf(x, k[2], bb[2]) + r * fmaf(h, rk[2], bb[5]));
  return z * h + (1.f - z) * hh;
}

// 3 tiny sequential bidirectional GRU chains + softmax + gather -> tp[3][60]
__global__ void __launch_bounds__(64, 1)
temporal_kernel(const float* __restrict__ T, const float* __restrict__ GK,
                const float* __restrict__ GRK, const float* __restrict__ GB,
                const float* __restrict__ WO, const int* __restrict__ IDX,
                float* __restrict__ tp) {
  const int i = threadIdx.x;
  __shared__ float fb[3][75];
  __shared__ float gg[3][75];
  if (i < 3) {
    float k0[3], k1[3], rk0[3], rk1[3];
#pragma unroll
    for (int q = 0; q < 3; ++q) {
      k0[q]  = GK[i * 6 + q];      k1[q]  = GK[i * 6 + 3 + q];
      rk0[q] = GRK[i * 6 + q];     rk1[q] = GRK[i * 6 + 3 + q];
    }
    const float* B0 = GB + i * 12;
    const float* B1 = GB + i * 12 + 6;
    float h = 0.f;
    for (int s = 0; s < 75; ++s) { h = gstep(T[i * 75 + s], h, k0, rk0, B0); fb[i][s] = h; }
    h = 0.f;
    for (int s = 0; s < 75; ++s) { h = gstep(fb[i][74 - s], h, k1, rk1, B1); gg[i][s] = h; }
    const float wo = WO[i];
    float mx = -1e30f;
    for (int s = 0; s < 75; ++s) mx = fmaxf(mx, gg[i][s] * wo);
    float sum = 0.f;
    for (int s = 0; s < 75; ++s) { const float e = __expf(gg[i][s] * wo - mx); fb[i][s] = e; sum += e; }
    const float inv = 1.f / sum;
    for (int j = 0; j < 60; ++j) tp[i * 60 + j] = fb[i][IDX[j]] * inv;
  }
}

// One wave per batch element, lane = feature column c.  Round-4 structure
// (zero spill, LDS-staged gate operands) with the staging region TIME-SHARED:
//   phase A: gate O uses smem[0..1919]  (10 rows x stride 192)
//   phase B: gates D+R reuse smem[0..1663] (11 x 128 for D, [1408..1535] for R)
// Only nR + nD0..10 (12 scalars) persist across gate O. LDS/block = 9.6 KB
// -> 16 blocks/CU (was 10), attacking the round-4 latency-bound regime.
__global__ void __launch_bounds__(64, 3) ggnn_main(
    const float* __restrict__ X, const float* __restrict__ A,
    const float* __restrict__ WgR, const float* __restrict__ bgR,
    const float* __restrict__ WgO, const float* __restrict__ bgO,
    const float* __restrict__ WgD, const float* __restrict__ bgD,
    const float* __restrict__ WzR, const float* __restrict__ WrR,
    const float* __restrict__ WmR, const float* __restrict__ bmR,
    const float* __restrict__ WzO, const float* __restrict__ WrO,
    const float* __restrict__ WmO, const float* __restrict__ bmO,
    const float* __restrict__ WzD, const float* __restrict__ WrD,
    const float* __restrict__ WmD, const float* __restrict__ bmD,
    const float* __restrict__ W1R, const float* __restrict__ b1R, const float* __restrict__ W2R,
    const float* __restrict__ W1O, const float* __restrict__ b1O, const float* __restrict__ W2O,
    const float* __restrict__ W1D, const float* __restrict__ b1D, const float* __restrict__ W2D,
    const float* __restrict__ tp, float* __restrict__ out) {
  const int b = blockIdx.x;
  const int c = threadIdx.x;  // 0..63

  __shared__ __align__(16) float smem[1920];  // X stage / O stage / D+R stage / score stash
  __shared__ float sA[484];                   // A[b] 22x22

  const float* Xb = X + (size_t)b * 880;
  const float* Ab = A + (size_t)b * 484;
  for (int t = c; t < 880; t += 64) smem[t] = Xb[t];
  for (int t = c; t < 484; t += 64) sA[t] = Ab[t];
  __syncthreads();

  // ---------------- phase 0: h = tanh(Xg @ Wg + bg) ----------------
  float hR;
#define DECLHO(i) float hO##i;
  R10(DECLHO)
#undef DECLHO
#define DECLHD(i) float hD##i;
  R11(DECLHD)
#undef DECLHD
  {
    float aR = bgR[c], cO = bgO[c], cD = bgD[c];
#pragma unroll 4
    for (int k = 0; k < 40; ++k) {
      const float x = smem[k];
      aR = fmaf(x, WgR[k * 64 + c], aR);
      cO = fmaf(x, WgO[k * 64 + c], cO);
      cD = fmaf(x, WgD[k * 64 + c], cD);
    }
    hR = tanhf(aR);
#define DECLAO(i) float aO##i = cO;
    R10(DECLAO)
#undef DECLAO
#define DECLAD(i) float aD##i = cD;
    R11(DECLAD)
#undef DECLAD
#pragma unroll 2
    for (int k = 0; k < 30; ++k) {
      const float wo_ = WgO[(40 + k) * 64 + c];
      const float wd_ = WgD[(40 + k) * 64 + c];
#define AOSTEP(i) aO##i = fmaf(smem[(1 + i) * 40 + 10 + k], wo_, aO##i);
      R10(AOSTEP)
#undef AOSTEP
#define ADSTEP(i) aD##i = fmaf(smem[(11 + i) * 40 + 10 + k], wd_, aD##i);
      R11(ADSTEP)
#undef ADSTEP
    }
#define TANHO(i) hO##i = tanhf(aO##i);
    R10(TANHO)
#undef TANHO
#define TANHD(i) hD##i = tanhf(aD##i);
    R11(TANHD)
#undef TANHD
  }

  // ---------------- 3 GRU iterations ----------------
  for (int it = 0; it < 3; ++it) {
    // snapshot the messages that depend on OLD hO (gate O will overwrite hO)
    const float nR = DOT_O(1);
#define DECLND(i) const float nD##i = DOT_O((11 + i) * 22 + 1);
    R11(DECLND)
#undef DECLND

    // ---- phase A: gate O (10 rows, K=192), staging region [0..1919] ----
    __syncthreads();  // prior-phase LDS reads done
#define STAGEO(i) smem[i * 192 + c] = hO##i; \
                  smem[i * 192 + 64 + c] = sA[(1 + i) * 22] * hR; \
                  smem[i * 192 + 128 + c] = DOT_D((1 + i) * 22 + 11);
    R10(STAGEO)
#undef STAGEO
    __syncthreads();
    {
#define DECLZR(i) float az##i = 0.f, ar##i = 0.f;
      R10(DECLZR)
#undef DECLZR
#pragma unroll 2
      for (int k4 = 0; k4 < 192; k4 += 4) {
        const float wa0 = WzO[(k4 + 0) * 64 + c], wa1 = WzO[(k4 + 1) * 64 + c];
        const float wa2 = WzO[(k4 + 2) * 64 + c], wa3 = WzO[(k4 + 3) * 64 + c];
        const float wb0 = WrO[(k4 + 0) * 64 + c], wb1 = WrO[(k4 + 1) * 64 + c];
        const float wb2 = WrO[(k4 + 2) * 64 + c], wb3 = WrO[(k4 + 3) * 64 + c];
#define MSTEP(i) { const float4 v = *reinterpret_cast<const float4*>(&smem[i * 192 + k4]); \
        az##i = fmaf(v.x, wa0, az##i); az##i = fmaf(v.y, wa1, az##i); \
        az##i = fmaf(v.z, wa2, az##i); az##i = fmaf(v.w, wa3, az##i); \
        ar##i = fmaf(v.x, wb0, ar##i); ar##i = fmaf(v.y, wb1, ar##i); \
        ar##i = fmaf(v.z, wb2, ar##i); ar##i = fmaf(v.w, wb3, ar##i); }
        R10(MSTEP)
#undef MSTEP
      }
#define SIGZR(i) const float z##i = sigmoidf_(az##i); const float r##i = sigmoidf_(ar##i);
      R10(SIGZR)
#undef SIGZR
      __syncthreads();
#define STAGEHR(i) smem[i * 192 + c] = hO##i * r##i;
      R10(STAGEHR)
#undef STAGEHR
      __syncthreads();
#define DECLAM(i) float am##i = bmO[c];
      R10(DECLAM)
#undef DECLAM
#pragma unroll 2
      for (int k4 = 0; k4 < 192; k4 += 4) {
        const float w0 = WmO[(k4 + 0) * 64 + c], w1 = WmO[(k4 + 1) * 64 + c];
        const float w2 = WmO[(k4 + 2) * 64 + c], w3 = WmO[(k4 + 3) * 64 + c];
#define MSTEP(i) { const float4 v = *reinterpret_cast<const float4*>(&smem[i * 192 + k4]); \
        am##i = fmaf(v.x, w0, am##i); am##i = fmaf(v.y, w1, am##i); \
        am##i = fmaf(v.z, w2, am##i); am##i = fmaf(v.w, w3, am##i); }
        R10(MSTEP)
#undef MSTEP
      }
#define UPDO(i) hO##i = (1.f - z##i) * hO##i + z##i * tanhf(am##i);
      R10(UPDO)
#undef UPDO
    }

    // ---- phase B: gates D (11 rows, K=128, region [0..1407]) + R ([1408..1535]) ----
    __syncthreads();  // O-phase m reads done; region is dead
#define STAGEDD(i) smem[i * 128 + c] = hD##i; \
                   smem[i * 128 + 64 + c] = nD##i;
    R11(STAGEDD)
#undef STAGEDD
    smem[1408 + c] = hR;
    smem[1472 + c] = nR;
    __syncthreads();
    {
#define DECLZR(i) float az##i = 0.f, ar##i = 0.f;
      R11(DECLZR)
#undef DECLZR
      float azR = 0.f, arR = 0.f;
#pragma unroll 2
      for (int k4 = 0; k4 < 128; k4 += 4) {
        const float wa0 = WzD[(k4 + 0) * 64 + c], wa1 = WzD[(k4 + 1) * 64 + c];
        const float wa2 = WzD[(k4 + 2) * 64 + c], wa3 = WzD[(k4 + 3) * 64 + c];
        const float wb0 = WrD[(k4 + 0) * 64 + c], wb1 = WrD[(k4 + 1) * 64 + c];
        const float wb2 = WrD[(k4 + 2) * 64 + c], wb3 = WrD[(k4 + 3) * 64 + c];
#define MSTEP(i) { const float4 v = *reinterpret_cast<const float4*>(&smem[i * 128 + k4]); \
        az##i = fmaf(v.x, wa0, az##i); az##i = fmaf(v.y, wa1, az##i); \
        az##i = fmaf(v.z, wa2, az##i); az##i = fmaf(v.w, wa3, az##i); \
        ar##i = fmaf(v.x, wb0, ar##i); ar##i = fmaf(v.y, wb1, ar##i); \
        ar##i = fmaf(v.z, wb2, ar##i); ar##i = fmaf(v.w, wb3, ar##i); }
        R11(MSTEP)
#undef MSTEP
        const float wza0 = WzR[(k4 + 0) * 64 + c], wza1 = WzR[(k4 + 1) * 64 + c];
        const float wza2 = WzR[(k4 + 2) * 64 + c], wza3 = WzR[(k4 + 3) * 64 + c];
        const float wra0 = WrR[(k4 + 0) * 64 + c], wra1 = WrR[(k4 + 1) * 64 + c];
        const float wra2 = WrR[(k4 + 2) * 64 + c], wra3 = WrR[(k4 + 3) * 64 + c];
        const float4 vr = *reinterpret_cast<const float4*>(&smem[1408 + k4]);
        azR = fmaf(vr.x, wza0, azR); azR = fmaf(vr.y, wza1, azR);
        azR = fmaf(vr.z, wza2, azR); azR = fmaf(vr.w, wza3, azR);
        arR = fmaf(vr.x, wra0, arR); arR = fmaf(vr.y, wra1, arR);
        arR = fmaf(vr.z, wra2, arR); arR = fmaf(vr.w, wra3, arR);
      }
#define SIGZR(i) const float z##i = sigmoidf_(az##i); const float r##i = sigmoidf_(ar##i);
      R11(SIGZR)
#undef SIGZR
      const float zR_ = sigmoidf_(azR);
      const float rR_ = sigmoidf_(arR);
      __syncthreads();
#define STAGEHR(i) smem[i * 128 + c] = hD##i * r##i;
      R11(STAGEHR)
#undef STAGEHR
      smem[1408 + c] = hR * rR_;
      __syncthreads();
#define DECLAM(i) float am##i = bmD[c];
      R11(DECLAM)
#undef DECLAM
      float amR = bmR[c];
#pragma unroll 2
      for (int k4 = 0; k4 < 128; k4 += 4) {
        const float w0 = WmD[(k4 + 0) * 64 + c], w1 = WmD[(k4 + 1) * 64 + c];
        const float w2 = WmD[(k4 + 2) * 64 + c], w3 = WmD[(k4 + 3) * 64 + c];
#define MSTEP(i) { const float4 v = *reinterpret_cast<const float4*>(&smem[i * 128 + k4]); \
        am##i = fmaf(v.x, w0, am##i); am##i = fmaf(v.y, w1, am##i); \
        am##i = fmaf(v.z, w2, am##i); am##i = fmaf(v.w, w3, am##i); }
        R11(MSTEP)
#undef MSTEP
        const float wm0 = WmR[(k4 + 0) * 64 + c], wm1 = WmR[(k4 + 1) * 64 + c];
        const float wm2 = WmR[(k4 + 2) * 64 + c], wm3 = WmR[(k4 + 3) * 64 + c];
        const float4 vr = *reinterpret_cast<const float4*>(&smem[1408 + k4]);
        amR = fmaf(vr.x, wm0, amR); amR = fmaf(vr.y, wm1, amR);
        amR = fmaf(vr.z, wm2, amR); amR = fmaf(vr.w, wm3, amR);
      }
#define UPDD(i) hD##i = (1.f - z##i) * hD##i + z##i * tanhf(am##i);
      R11(UPDD)
#undef UPDD
      hR = (1.f - zR_) * hR + zR_ * tanhf(amR);
    }
  }

  // ---------------- scores ----------------
  __syncthreads();
  smem[c] = hR;
#define STASH_O(i) smem[(1 + i) * 64 + c] = hO##i;
  R10(STASH_O)
#undef STASH_O
#define STASH_D(i) smem[(11 + i) * 64 + c] = hD##i;
  R11(STASH_D)
#undef STASH_D
  __syncthreads();

  const int g = c >> 4;    // row-group 0..3
  const int c1 = c & 15;   // hidden-1 column
  float pR = 0.f, pO = 0.f, pD = 0.f;
  for (int rr = g; rr < 22; rr += 4) {
    const float* W1; const float* b1; const float* W2;
    if (rr == 0)      { W1 = W1R; b1 = b1R; W2 = W2R; }
    else if (rr < 11) { W1 = W1O; b1 = b1O; W2 = W2O; }
    else              { W1 = W1D; b1 = b1D; W2 = W2D; }
    float a = b1[c1];
#pragma unroll 8
    for (int kk = 0; kk < 64; ++kk) {
      const int k = (kk + (g << 4)) & 63;  // stagger to dodge LDS bank aliasing
      a = fmaf(smem[rr * 64 + k], W1[k * 16 + c1], a);
    }
    const float t = tanhf(a) * W2[c1];
    if (rr == 0) pR += t;
    else if (rr < 11) pO += t;
    else pD += t;
  }
#pragma unroll
  for (int off = 32; off >= 1; off >>= 1) {
    pR += __shfl_xor(pR, off, 64);
    pO += __shfl_xor(pO, off, 64);
    pD += __shfl_xor(pD, off, 64);
  }
  if (c < 60) {
    out[(size_t)b * 60 + c] = pR * tp[c] + pO * tp[60 + c] + pD * tp[120 + c];
  }
}

extern "C" void kernel_launch(void* const* d_in, const int* in_sizes, int n_in,
                              void* d_out, int out_size, void* d_ws, size_t ws_size,
                              hipStream_t stream) {
  const float* X   = (const float*)d_in[0];
  const float* A   = (const float*)d_in[1];
  const float* WgR = (const float*)d_in[2];
  const float* bgR = (const float*)d_in[3];
  const float* WgO = (const float*)d_in[4];
  const float* bgO = (const float*)d_in[5];
  const float* WgD = (const float*)d_in[6];
  const float* bgD = (const float*)d_in[7];
  const float* WzR = (const float*)d_in[8];
  const float* WrR = (const float*)d_in[9];
  const float* WmR = (const float*)d_in[10];
  const float* bmR = (const float*)d_in[11];
  const float* WzO = (const float*)d_in[12];
  const float* WrO = (const float*)d_in[13];
  const float* WmO = (const float*)d_in[14];
  const float* bmO = (const float*)d_in[15];
  const float* WzD = (const float*)d_in[16];
  const float* WrD = (const float*)d_in[17];
  const float* WmD = (const float*)d_in[18];
  const float* bmD = (const float*)d_in[19];
  const float* W1R = (const float*)d_in[20];
  const float* b1R = (const float*)d_in[21];
  const float* W2R = (const float*)d_in[22];
  const float* W1O = (const float*)d_in[23];
  const float* b1O = (const float*)d_in[24];
  const float* W2O = (const float*)d_in[25];
  const float* W1D = (const float*)d_in[26];
  const float* b1D = (const float*)d_in[27];
  const float* W2D = (const float*)d_in[28];
  const float* Tmp = (const float*)d_in[29];
  const float* GK  = (const float*)d_in[30];
  const float* GRK = (const float*)d_in[31];
  const float* GB  = (const float*)d_in[32];
  const float* WO  = (const float*)d_in[33];
  const int*   IDX = (const int*)d_in[34];

  float* tp = (float*)d_ws;  // 3*60 floats
  const int B = in_sizes[0] / 880;

  hipLaunchKernelGGL(temporal_kernel, dim3(1), dim3(64), 0, stream, Tmp, GK, GRK, GB, WO, IDX, tp);
  hipLaunchKernelGGL(ggnn_main, dim3(B), dim3(64), 0, stream,
                     X, A, WgR, bgR, WgO, bgO, WgD, bgD,
                     WzR, WrR, WmR, bmR, WzO, WrO, WmO, bmO, WzD, WrD, WmD, bmD,
                     W1R, b1R, W2R, W1O, b1O, W2O, W1D, b1D, W2D,
                     tp, (float*)d_out);
}

// Round 8
// 1092.662 us; speedup vs baseline: 2.8792x; 1.0370x over previous
//
#include <hip/hip_runtime.h>
#include <hip/hip_bf16.h>
#include <math.h>

#define DEV __device__ __forceinline__

DEV float sigmoidf_(float x) { return 1.0f / (1.0f + __expf(-x)); }

#define R10(OP) OP(0) OP(1) OP(2) OP(3) OP(4) OP(5) OP(6) OP(7) OP(8) OP(9)
#define R11(OP) R10(OP) OP(10)

// dot of sA[base..base+9] with hO scalars (sA entries are wave-uniform)
#define DOT_O(base) (sA[(base)+0]*hO0 + sA[(base)+1]*hO1 + sA[(base)+2]*hO2 + sA[(base)+3]*hO3 \
                   + sA[(base)+4]*hO4 + sA[(base)+5]*hO5 + sA[(base)+6]*hO6 + sA[(base)+7]*hO7 \
                   + sA[(base)+8]*hO8 + sA[(base)+9]*hO9)
#define DOT_D(base) (sA[(base)+0]*hD0 + sA[(base)+1]*hD1 + sA[(base)+2]*hD2 + sA[(base)+3]*hD3 \
                   + sA[(base)+4]*hD4 + sA[(base)+5]*hD5 + sA[(base)+6]*hD6 + sA[(base)+7]*hD7 \
                   + sA[(base)+8]*hD8 + sA[(base)+9]*hD9 + sA[(base)+10]*hD10)

DEV float gstep(float x, float h, const float* k, const float* rk, const float* bb) {
  const float z  = sigmoidf_(fmaf(x, k[0], bb[0]) + fmaf(h, rk[0], bb[3]));
  const float r  = sigmoidf_(fmaf(x, k[1], bb[1]) + fmaf(h, rk[1], bb[4]));
  const float hh = tanhf(fmaf(x, k[2], bb[2]) + r * fmaf(h, rk[2], bb[5]));
  return z * h + (1.f - z) * hh;
}

// 3 tiny sequential bidirectional GRU chains + softmax + gather -> tp[3][60]
__global__ void __launch_bounds__(64, 1)
temporal_kernel(const float* __restrict__ T, const float* __restrict__ GK,
                const float* __restrict__ GRK, const float* __restrict__ GB,
                const float* __restrict__ WO, const int* __restrict__ IDX,
                float* __restrict__ tp) {
  const int i = threadIdx.x;
  __shared__ float fb[3][75];
  __shared__ float gg[3][75];
  if (i < 3) {
    float k0[3], k1[3], rk0[3], rk1[3];
#pragma unroll
    for (int q = 0; q < 3; ++q) {
      k0[q]  = GK[i * 6 + q];      k1[q]  = GK[i * 6 + 3 + q];
      rk0[q] = GRK[i * 6 + q];     rk1[q] = GRK[i * 6 + 3 + q];
    }
    const float* B0 = GB + i * 12;
    const float* B1 = GB + i * 12 + 6;
    float h = 0.f;
    for (int s = 0; s < 75; ++s) { h = gstep(T[i * 75 + s], h, k0, rk0, B0); fb[i][s] = h; }
    h = 0.f;
    for (int s = 0; s < 75; ++s) { h = gstep(fb[i][74 - s], h, k1, rk1, B1); gg[i][s] = h; }
    const float wo = WO[i];
    float mx = -1e30f;
    for (int s = 0; s < 75; ++s) mx = fmaxf(mx, gg[i][s] * wo);
    float sum = 0.f;
    for (int s = 0; s < 75; ++s) { const float e = __expf(gg[i][s] * wo - mx); fb[i][s] = e; sum += e; }
    const float inv = 1.f / sum;
    for (int j = 0; j < 60; ++j) tp[i * 60 + j] = fb[i][IDX[j]] * inv;
  }
}

// One wave per batch element, lane = feature column c.  Round-7 time-shared
// staging (9.7 KB LDS -> 16 blocks/CU) with launch_bounds REVERTED to (64,2):
// session evidence says this kernel family needs ~128 VGPRs; (64,3) capped at
// 84 and re-spilled (536 MB scratch). (64,2) is the only proven no-spill cap.
//   phase A: gate O uses smem[0..1919]  (10 rows x stride 192)
//   phase B: gates D+R reuse smem[0..1535] (11 x 128 for D, [1408..1535] for R)
__global__ void __launch_bounds__(64, 2) ggnn_main(
    const float* __restrict__ X, const float* __restrict__ A,
    const float* __restrict__ WgR, const float* __restrict__ bgR,
    const float* __restrict__ WgO, const float* __restrict__ bgO,
    const float* __restrict__ WgD, const float* __restrict__ bgD,
    const float* __restrict__ WzR, const float* __restrict__ WrR,
    const float* __restrict__ WmR, const float* __restrict__ bmR,
    const float* __restrict__ WzO, const float* __restrict__ WrO,
    const float* __restrict__ WmO, const float* __restrict__ bmO,
    const float* __restrict__ WzD, const float* __restrict__ WrD,
    const float* __restrict__ WmD, const float* __restrict__ bmD,
    const float* __restrict__ W1R, const float* __restrict__ b1R, const float* __restrict__ W2R,
    const float* __restrict__ W1O, const float* __restrict__ b1O, const float* __restrict__ W2O,
    const float* __restrict__ W1D, const float* __restrict__ b1D, const float* __restrict__ W2D,
    const float* __restrict__ tp, float* __restrict__ out) {
  const int b = blockIdx.x;
  const int c = threadIdx.x;  // 0..63

  __shared__ __align__(16) float smem[1920];  // X stage / O stage / D+R stage / score stash
  __shared__ float sA[484];                   // A[b] 22x22

  const float* Xb = X + (size_t)b * 880;
  const float* Ab = A + (size_t)b * 484;
  for (int t = c; t < 880; t += 64) smem[t] = Xb[t];
  for (int t = c; t < 484; t += 64) sA[t] = Ab[t];
  __syncthreads();

  // ---------------- phase 0: h = tanh(Xg @ Wg + bg) ----------------
  float hR;
#define DECLHO(i) float hO##i;
  R10(DECLHO)
#undef DECLHO
#define DECLHD(i) float hD##i;
  R11(DECLHD)
#undef DECLHD
  {
    float aR = bgR[c], cO = bgO[c], cD = bgD[c];
#pragma unroll 4
    for (int k = 0; k < 40; ++k) {
      const float x = smem[k];
      aR = fmaf(x, WgR[k * 64 + c], aR);
      cO = fmaf(x, WgO[k * 64 + c], cO);
      cD = fmaf(x, WgD[k * 64 + c], cD);
    }
    hR = tanhf(aR);
#define DECLAO(i) float aO##i = cO;
    R10(DECLAO)
#undef DECLAO
#define DECLAD(i) float aD##i = cD;
    R11(DECLAD)
#undef DECLAD
#pragma unroll 2
    for (int k = 0; k < 30; ++k) {
      const float wo_ = WgO[(40 + k) * 64 + c];
      const float wd_ = WgD[(40 + k) * 64 + c];
#define AOSTEP(i) aO##i = fmaf(smem[(1 + i) * 40 + 10 + k], wo_, aO##i);
      R10(AOSTEP)
#undef AOSTEP
#define ADSTEP(i) aD##i = fmaf(smem[(11 + i) * 40 + 10 + k], wd_, aD##i);
      R11(ADSTEP)
#undef ADSTEP
    }
#define TANHO(i) hO##i = tanhf(aO##i);
    R10(TANHO)
#undef TANHO
#define TANHD(i) hD##i = tanhf(aD##i);
    R11(TANHD)
#undef TANHD
  }

  // ---------------- 3 GRU iterations ----------------
  for (int it = 0; it < 3; ++it) {
    // snapshot the messages that depend on OLD hO (gate O will overwrite hO)
    const float nR = DOT_O(1);
#define DECLND(i) const float nD##i = DOT_O((11 + i) * 22 + 1);
    R11(DECLND)
#undef DECLND

    // ---- phase A: gate O (10 rows, K=192), staging region [0..1919] ----
    __syncthreads();  // prior-phase LDS reads done
#define STAGEO(i) smem[i * 192 + c] = hO##i; \
                  smem[i * 192 + 64 + c] = sA[(1 + i) * 22] * hR; \
                  smem[i * 192 + 128 + c] = DOT_D((1 + i) * 22 + 11);
    R10(STAGEO)
#undef STAGEO
    __syncthreads();
    {
#define DECLZR(i) float az##i = 0.f, ar##i = 0.f;
      R10(DECLZR)
#undef DECLZR
#pragma unroll 2
      for (int k4 = 0; k4 < 192; k4 += 4) {
        const float wa0 = WzO[(k4 + 0) * 64 + c], wa1 = WzO[(k4 + 1) * 64 + c];
        const float wa2 = WzO[(k4 + 2) * 64 + c], wa3 = WzO[(k4 + 3) * 64 + c];
        const float wb0 = WrO[(k4 + 0) * 64 + c], wb1 = WrO[(k4 + 1) * 64 + c];
        const float wb2 = WrO[(k4 + 2) * 64 + c], wb3 = WrO[(k4 + 3) * 64 + c];
#define MSTEP(i) { const float4 v = *reinterpret_cast<const float4*>(&smem[i * 192 + k4]); \
        az##i = fmaf(v.x, wa0, az##i); az##i = fmaf(v.y, wa1, az##i); \
        az##i = fmaf(v.z, wa2, az##i); az##i = fmaf(v.w, wa3, az##i); \
        ar##i = fmaf(v.x, wb0, ar##i); ar##i = fmaf(v.y, wb1, ar##i); \
        ar##i = fmaf(v.z, wb2, ar##i); ar##i = fmaf(v.w, wb3, ar##i); }
        R10(MSTEP)
#undef MSTEP
      }
#define SIGZR(i) const float z##i = sigmoidf_(az##i); const float r##i = sigmoidf_(ar##i);
      R10(SIGZR)
#undef SIGZR
      __syncthreads();
#define STAGEHR(i) smem[i * 192 + c] = hO##i * r##i;
      R10(STAGEHR)
#undef STAGEHR
      __syncthreads();
#define DECLAM(i) float am##i = bmO[c];
      R10(DECLAM)
#undef DECLAM
#pragma unroll 2
      for (int k4 = 0; k4 < 192; k4 += 4) {
        const float w0 = WmO[(k4 + 0) * 64 + c], w1 = WmO[(k4 + 1) * 64 + c];
        const float w2 = WmO[(k4 + 2) * 64 + c], w3 = WmO[(k4 + 3) * 64 + c];
#define MSTEP(i) { const float4 v = *reinterpret_cast<const float4*>(&smem[i * 192 + k4]); \
        am##i = fmaf(v.x, w0, am##i); am##i = fmaf(v.y, w1, am##i); \
        am##i = fmaf(v.z, w2, am##i); am##i = fmaf(v.w, w3, am##i); }
        R10(MSTEP)
#undef MSTEP
      }
#define UPDO(i) hO##i = (1.f - z##i) * hO##i + z##i * tanhf(am##i);
      R10(UPDO)
#undef UPDO
    }

    // ---- phase B: gates D (11 rows, K=128, region [0..1407]) + R ([1408..1535]) ----
    __syncthreads();  // O-phase m reads done; region is dead
#define STAGEDD(i) smem[i * 128 + c] = hD##i; \
                   smem[i * 128 + 64 + c] = nD##i;
    R11(STAGEDD)
#undef STAGEDD
    smem[1408 + c] = hR;
    smem[1472 + c] = nR;
    __syncthreads();
    {
#define DECLZR(i) float az##i = 0.f, ar##i = 0.f;
      R11(DECLZR)
#undef DECLZR
      float azR = 0.f, arR = 0.f;
#pragma unroll 2
      for (int k4 = 0; k4 < 128; k4 += 4) {
        const float wa0 = WzD[(k4 + 0) * 64 + c], wa1 = WzD[(k4 + 1) * 64 + c];
        const float wa2 = WzD[(k4 + 2) * 64 + c], wa3 = WzD[(k4 + 3) * 64 + c];
        const float wb0 = WrD[(k4 + 0) * 64 + c], wb1 = WrD[(k4 + 1) * 64 + c];
        const float wb2 = WrD[(k4 + 2) * 64 + c], wb3 = WrD[(k4 + 3) * 64 + c];
#define MSTEP(i) { const float4 v = *reinterpret_cast<const float4*>(&smem[i * 128 + k4]); \
        az##i = fmaf(v.x, wa0, az##i); az##i = fmaf(v.y, wa1, az##i); \
        az##i = fmaf(v.z, wa2, az##i); az##i = fmaf(v.w, wa3, az##i); \
        ar##i = fmaf(v.x, wb0, ar##i); ar##i = fmaf(v.y, wb1, ar##i); \
        ar##i = fmaf(v.z, wb2, ar##i); ar##i = fmaf(v.w, wb3, ar##i); }
        R11(MSTEP)
#undef MSTEP
        const float wza0 = WzR[(k4 + 0) * 64 + c], wza1 = WzR[(k4 + 1) * 64 + c];
        const float wza2 = WzR[(k4 + 2) * 64 + c], wza3 = WzR[(k4 + 3) * 64 + c];
        const float wra0 = WrR[(k4 + 0) * 64 + c], wra1 = WrR[(k4 + 1) * 64 + c];
        const float wra2 = WrR[(k4 + 2) * 64 + c], wra3 = WrR[(k4 + 3) * 64 + c];
        const float4 vr = *reinterpret_cast<const float4*>(&smem[1408 + k4]);
        azR = fmaf(vr.x, wza0, azR); azR = fmaf(vr.y, wza1, azR);
        azR = fmaf(vr.z, wza2, azR); azR = fmaf(vr.w, wza3, azR);
        arR = fmaf(vr.x, wra0, arR); arR = fmaf(vr.y, wra1, arR);
        arR = fmaf(vr.z, wra2, arR); arR = fmaf(vr.w, wra3, arR);
      }
#define SIGZR(i) const float z##i = sigmoidf_(az##i); const float r##i = sigmoidf_(ar##i);
      R11(SIGZR)
#undef SIGZR
      const float zR_ = sigmoidf_(azR);
      const float rR_ = sigmoidf_(arR);
      __syncthreads();
#define STAGEHR(i) smem[i * 128 + c] = hD##i * r##i;
      R11(STAGEHR)
#undef STAGEHR
      smem[1408 + c] = hR * rR_;
      __syncthreads();
#define DECLAM(i) float am##i = bmD[c];
      R11(DECLAM)
#undef DECLAM
      float amR = bmR[c];
#pragma unroll 2
      for (int k4 = 0; k4 < 128; k4 += 4) {
        const float w0 = WmD[(k4 + 0) * 64 + c], w1 = WmD[(k4 + 1) * 64 + c];
        const float w2 = WmD[(k4 + 2) * 64 + c], w3 = WmD[(k4 + 3) * 64 + c];
#define MSTEP(i) { const float4 v = *reinterpret_cast<const float4*>(&smem[i * 128 + k4]); \
        am##i = fmaf(v.x, w0, am##i); am##i = fmaf(v.y, w1, am##i); \
        am##i = fmaf(v.z, w2, am##i); am##i = fmaf(v.w, w3, am##i); }
        R11(MSTEP)
#undef MSTEP
        const float wm0 = WmR[(k4 + 0) * 64 + c], wm1 = WmR[(k4 + 1) * 64 + c];
        const float wm2 = WmR[(k4 + 2) * 64 + c], wm3 = WmR[(k4 + 3) * 64 + c];
        const float4 vr = *reinterpret_cast<const float4*>(&smem[1408 + k4]);
        amR = fmaf(vr.x, wm0, amR); amR = fmaf(vr.y, wm1, amR);
        amR = fmaf(vr.z, wm2, amR); amR = fmaf(vr.w, wm3, amR);
      }
#define UPDD(i) hD##i = (1.f - z##i) * hD##i + z##i * tanhf(am##i);
      R11(UPDD)
#undef UPDD
      hR = (1.f - zR_) * hR + zR_ * tanhf(amR);
    }
  }

  // ---------------- scores ----------------
  __syncthreads();
  smem[c] = hR;
#define STASH_O(i) smem[(1 + i) * 64 + c] = hO##i;
  R10(STASH_O)
#undef STASH_O
#define STASH_D(i) smem[(11 + i) * 64 + c] = hD##i;
  R11(STASH_D)
#undef STASH_D
  __syncthreads();

  const int g = c >> 4;    // row-group 0..3
  const int c1 = c & 15;   // hidden-1 column
  float pR = 0.f, pO = 0.f, pD = 0.f;
  for (int rr = g; rr < 22; rr += 4) {
    const float* W1; const float* b1; const float* W2;
    if (rr == 0)      { W1 = W1R; b1 = b1R; W2 = W2R; }
    else if (rr < 11) { W1 = W1O; b1 = b1O; W2 = W2O; }
    else              { W1 = W1D; b1 = b1D; W2 = W2D; }
    float a = b1[c1];
#pragma unroll 8
    for (int kk = 0; kk < 64; ++kk) {
      const int k = (kk + (g << 4)) & 63;  // stagger to dodge LDS bank aliasing
      a = fmaf(smem[rr * 64 + k], W1[k * 16 + c1], a);
    }
    const float t = tanhf(a) * W2[c1];
    if (rr == 0) pR += t;
    else if (rr < 11) pO += t;
    else pD += t;
  }
#pragma unroll
  for (int off = 32; off >= 1; off >>= 1) {
    pR += __shfl_xor(pR, off, 64);
    pO += __shfl_xor(pO, off, 64);
    pD += __shfl_xor(pD, off, 64);
  }
  if (c < 60) {
    out[(size_t)b * 60 + c] = pR * tp[c] + pO * tp[60 + c] + pD * tp[120 + c];
  }
}

extern "C" void kernel_launch(void* const* d_in, const int* in_sizes, int n_in,
                              void* d_out, int out_size, void* d_ws, size_t ws_size,
                              hipStream_t stream) {
  const float* X   = (const float*)d_in[0];
  const float* A   = (const float*)d_in[1];
  const float* WgR = (const float*)d_in[2];
  const float* bgR = (const float*)d_in[3];
  const float* WgO = (const float*)d_in[4];
  const float* bgO = (const float*)d_in[5];
  const float* WgD = (const float*)d_in[6];
  const float* bgD = (const float*)d_in[7];
  const float* WzR = (const float*)d_in[8];
  const float* WrR = (const float*)d_in[9];
  const float* WmR = (const float*)d_in[10];
  const float* bmR = (const float*)d_in[11];
  const float* WzO = (const float*)d_in[12];
  const float* WrO = (const float*)d_in[13];
  const float* WmO = (const float*)d_in[14];
  const float* bmO = (const float*)d_in[15];
  const float* WzD = (const float*)d_in[16];
  const float* WrD = (const float*)d_in[17];
  const float* WmD = (const float*)d_in[18];
  const float* bmD = (const float*)d_in[19];
  const float* W1R = (const float*)d_in[20];
  const float* b1R = (const float*)d_in[21];
  const float* W2R = (const float*)d_in[22];
  const float* W1O = (const float*)d_in[23];
  const float* b1O = (const float*)d_in[24];
  const float* W2O = (const float*)d_in[25];
  const float* W1D = (const float*)d_in[26];
  const float* b1D = (const float*)d_in[27];
  const float* W2D = (const float*)d_in[28];
  const float* Tmp = (const float*)d_in[29];
  const float* GK  = (const float*)d_in[30];
  const float* GRK = (const float*)d_in[31];
  const float* GB  = (const float*)d_in[32];
  const float* WO  = (const float*)d_in[33];
  const int*   IDX = (const int*)d_in[34];

  float* tp = (float*)d_ws;  // 3*60 floats
  const int B = in_sizes[0] / 880;

  hipLaunchKernelGGL(temporal_kernel, dim3(1), dim3(64), 0, stream, Tmp, GK, GRK, GB, WO, IDX, tp);
  hipLaunchKernelGGL(ggnn_main, dim3(B), dim3(64), 0, stream,
                     X, A, WgR, bgR, WgO, bgO, WgD, bgD,
                     WzR, WrR, WmR, bmR, WzO, WrO, WmO, bmO, WzD, WrD, WmD, bmD,
                     W1R, b1R, W2R, W1O, b1O, W2O, W1D, b1D, W2D,
                     tp, (float*)d_out);
}